// Round 1
// baseline (95.273 us; speedup 1.0000x reference)
//
#include <hip/hip_runtime.h>
#include <math.h>

#define B 4
#define N 4096
#define M 8192
#define C 64
#define NB 2048
#define XMIN (-64.0f)
#define INV_BW 16.0f   // bucket width 0.0625
#define CUT 10.0f      // truncation at exp(-10): err ~0.008 << tolerance
#define QG 16          // queries per group == MFMA M

typedef __attribute__((ext_vector_type(8))) short short8;   // 8 bf16
typedef __attribute__((ext_vector_type(4))) float f32x4;

__device__ __forceinline__ int bucket_of(float v) {
    int k = (int)floorf((v - XMIN) * INV_BW);
    return min(max(k, 0), NB - 1);
}

__device__ __forceinline__ unsigned short f2bf(float f) {   // RNE fp32->bf16
    unsigned int u = __float_as_uint(f);
    return (unsigned short)((u + 0x7FFF + ((u >> 16) & 1)) >> 16);
}

// Blocks 0..3: bin points (batch b) -> bucket_start, xs, iord (slot->m).
// Blocks 4..7: bin queries (batch b) -> qcs/qis. Wave-shuffle scan.
__global__ __launch_bounds__(1024) void bin_kernel(
    const float* __restrict__ xz, const float* __restrict__ x,
    int* __restrict__ bucket_start,    // [B][NB+1]
    float* __restrict__ xs,            // [B*M] sorted point coords
    int* __restrict__ iord,            // [B][M] sorted slot -> original m
    float* __restrict__ qcs,           // [B][N] sorted query coords
    int* __restrict__ qis)             // [B][N] sorted slot -> original n
{
    const int t    = threadIdx.x;
    const int lane = t & 63;
    const int w    = t >> 6;

    __shared__ int hist[NB];
    __shared__ int run[NB];
    __shared__ int wsum[16];
    const bool isQ = blockIdx.x >= 4;
    const int  b   = blockIdx.x & 3;
    const int  PT  = isQ ? (N / 1024) : (M / 1024);
    const float* src = isQ ? (x + b * N) : (xz + b * M);

    hist[t] = 0; hist[t + 1024] = 0;
    __syncthreads();

    float pv[8]; int pk[8];
    for (int j = 0; j < PT; ++j) {
        float v = src[j * 1024 + t];
        pv[j] = v; pk[j] = bucket_of(v);
        atomicAdd(&hist[pk[j]], 1);
    }
    __syncthreads();

    const int h0 = hist[2 * t], h1 = hist[2 * t + 1];
    const int tot = h0 + h1;
    int s = tot;
    #pragma unroll
    for (int off = 1; off < 64; off <<= 1) {
        int up = __shfl_up(s, off, 64);
        if (lane >= off) s += up;
    }
    if (lane == 63) wsum[w] = s;
    __syncthreads();
    int woff = 0;
    for (int i = 0; i < w; ++i) woff += wsum[i];
    const int excl = woff + s - tot;

    run[2 * t]     = excl;
    run[2 * t + 1] = excl + h0;
    if (!isQ) {
        bucket_start[b * (NB + 1) + 2 * t]     = excl;
        bucket_start[b * (NB + 1) + 2 * t + 1] = excl + h0;
        if (t == 1023) bucket_start[b * (NB + 1) + NB] = woff + s;  // == M
    }
    __syncthreads();

    if (!isQ) {
        for (int j = 0; j < PT; ++j) {
            int slot = atomicAdd(&run[pk[j]], 1);
            xs[b * M + slot]   = pv[j];
            iord[b * M + slot] = j * 1024 + t;
        }
    } else {
        for (int j = 0; j < PT; ++j) {
            int slot = atomicAdd(&run[pk[j]], 1);
            qcs[b * N + slot] = pv[j];
            qis[b * N + slot] = j * 1024 + t;
        }
    }
}

// 512 blocks (B x 128 chunks), 256 threads. Chunk-transposed bf16 layout:
// zs[b][chunk][c 0..63][64 points], with 16B blocks inside each 128B row
// XOR-swizzled by (c&7) so gather's ds_read_b128 (16 rows @128B stride) is
// bank-conflict-free. z rows are L2-resident (2MB/batch) -> scatter reads OK.
__global__ __launch_bounds__(256) void permz_kernel(
    const float* __restrict__ z, const int* __restrict__ iord,
    unsigned short* __restrict__ zs)   // [B][128][4096] ushort (8KB chunks)
{
    const int t    = threadIdx.x;
    const int lane = t & 63;           // lane == point slot within chunk
    const int w    = t >> 6;           // wave -> channels w*16..+15
    const int b    = blockIdx.x >> 7;
    const int ck   = blockIdx.x & 127;

    const int m = iord[b * M + ck * 64 + lane];          // sorted slot -> m
    const float* zb = z + (size_t)b * C * M;
    unsigned short* dst = zs + ((size_t)b * 128 + ck) * 4096;
    const int blk = lane >> 3;         // 16B block index within row
    const int lo  = lane & 7;

    float v[16];
    #pragma unroll
    for (int k = 0; k < 16; ++k)
        v[k] = zb[(size_t)(w * 16 + k) * M + m];         // scattered 4B, L2
    #pragma unroll
    for (int k = 0; k < 16; ++k) {
        const int c = w * 16 + k;
        dst[c * 64 + (((blk ^ (c & 7)) << 3) | lo)] = f2bf(v[k]);
    }
}

// One block per 16 sorted queries; 4 waves; mfma_f32_16x16x32_bf16.
// Double-buffered LDS (T3-lite): stage chunk i+1 + compute its weights while
// MFMA'ing chunk i -> ONE barrier per chunk. B-frag is a single ds_read_b128
// from the swizzled chunk-transposed tile. 64-aligned windows -> no masking
// (extra slots are real points with true (tiny) weights).
__global__ __launch_bounds__(256) void gather_kernel(
    const float* __restrict__ log_scale,
    const int* __restrict__ bucket_start,
    const float* __restrict__ xs,
    const float* __restrict__ qcs,
    const int* __restrict__ qis,
    const unsigned short* __restrict__ zs,   // chunk-transposed swizzled bf16
    float* __restrict__ out)                 // [B][N][C]
{
    const int t    = threadIdx.x;
    const int lane = t & 63;
    const int w    = t >> 6;            // wave 0..3 -> channels w*16..+15
    const int quad = lane >> 4;         // 0..3
    const int low4 = lane & 15;
    // XCD-aware bijective swizzle (1024 blocks, 1024%8==0): neighbors same XCD
    const int gid = blockIdx.x;
    const int swz = (gid & 7) * 128 + (gid >> 3);
    const int b   = swz >> 8;           // 256 groups per batch
    const int g0  = (swz & 255) * QG;

    __shared__ unsigned short zr[2][64 * 64];  // 2 x 8KB chunk tiles
    __shared__ unsigned short wl[2][QG][72];   // 2 x padded weight tiles
    __shared__ float qcS[QG];
    __shared__ int   qiS[QG];

    const float ls   = log_scale[0];
    const float coef = -0.5f * __expf(-2.0f * ls);   // negative
    const float R    = sqrtf(CUT / (-coef));

    if (t < QG) {
        qcS[t] = qcs[b * N + g0 + t];
        qiS[t] = qis[b * N + g0 + t];
    }
    __syncthreads();

    float xmin = qcS[0], xmax = qcS[0];
    #pragma unroll
    for (int j = 1; j < QG; ++j) {
        xmin = fminf(xmin, qcS[j]);
        xmax = fmaxf(xmax, qcS[j]);
    }
    const int s0 = bucket_start[b * (NB + 1) + bucket_of(xmin - R)];
    const int s1 = bucket_start[b * (NB + 1) + bucket_of(xmax + R) + 1];
    const int e0 = s0 & ~63;                 // 64-aligned window; M%64==0
    const int e1 = (s1 + 63) & ~63;          // so [e0,e1) stays in [0,M]
    const int nck = (e1 - e0) >> 6;

    // weight-phase mapping: this lane computes query qw, points pg*4..+3
    const int qw  = w * 4 + quad;            // 0..15
    const int pg  = low4;                    // point group (x4)
    const float qv = qcS[qw];
    const int row = w * 16 + low4;           // this lane's B-frag channel row

    const float* xsb = xs + b * M;
    const unsigned short* zcb = zs + (size_t)b * M * C;  // 128 chunks x 4096

    f32x4 acc = {0.f, 0.f, 0.f, 0.f};

    // stage chunk i into LDS buffer p (async) + compute its weights into wl[p]
    auto STAGE_W = [&](int i, int p) {
        const unsigned short* gsrc =
            zcb + ((size_t)((e0 >> 6) + i)) * 4096 + (w * 2) * 512 + lane * 8;
        __builtin_amdgcn_global_load_lds(
            (const __attribute__((address_space(1))) void*)gsrc,
            (__attribute__((address_space(3))) void*)(&zr[p][(w * 2) * 512]),
            16, 0, 0);
        __builtin_amdgcn_global_load_lds(
            (const __attribute__((address_space(1))) void*)(gsrc + 512),
            (__attribute__((address_space(3))) void*)(&zr[p][(w * 2 + 1) * 512]),
            16, 0, 0);
        const float4 xp4 = *(const float4*)(xsb + e0 + i * 64 + pg * 4);
        float d0 = qv - xp4.x, d1 = qv - xp4.y;
        float d2 = qv - xp4.z, d3 = qv - xp4.w;
        ushort4 wv;
        wv.x = f2bf(__expf(coef * d0 * d0));
        wv.y = f2bf(__expf(coef * d1 * d1));
        wv.z = f2bf(__expf(coef * d2 * d2));
        wv.w = f2bf(__expf(coef * d3 * d3));
        *(ushort4*)&wl[p][qw][pg * 4] = wv;
    };

    if (nck > 0) STAGE_W(0, 0);
    __syncthreads();                          // zr[0]/wl[0] ready

    for (int i = 0; i < nck; ++i) {
        const int cur = i & 1;
        if (i + 1 < nck) STAGE_W(i + 1, cur ^ 1);   // overlaps MFMA below
        #pragma unroll
        for (int kh = 0; kh < 2; ++kh) {
            short8 afrag = *(const short8*)&wl[cur][low4][kh * 32 + quad * 8];
            short8 bfrag = *(const short8*)
                &zr[cur][row * 64 + (((kh * 4 + quad) ^ (row & 7)) << 3)];
            acc = __builtin_amdgcn_mfma_f32_16x16x32_bf16(afrag, bfrag, acc, 0, 0, 0);
        }
        __syncthreads();                      // drains next-chunk loads + wl
    }

    // D: row(query) = quad*4 + r, col(channel local) = low4
    #pragma unroll
    for (int r = 0; r < 4; ++r) {
        const int q = quad * 4 + r;
        out[((size_t)b * N + qiS[q]) * C + w * 16 + low4] = acc[r];
    }
}

extern "C" void kernel_launch(void* const* d_in, const int* in_sizes, int n_in,
                              void* d_out, int out_size, void* d_ws, size_t ws_size,
                              hipStream_t stream) {
    const float* xz = (const float*)d_in[0];  // [B,M,1]
    const float* z  = (const float*)d_in[1];  // [B,C,M]
    const float* x  = (const float*)d_in[2];  // [B,N,1]
    const float* ls = (const float*)d_in[3];  // scalar
    float* out = (float*)d_out;               // [B,N,C]

    char* ws = (char*)d_ws;
    size_t off = 0;
    auto alloc = [&](size_t bytes) { void* p = ws + off; off += (bytes + 255) & ~size_t(255); return p; };

    unsigned short* zs = (unsigned short*)alloc((size_t)B * M * C * sizeof(unsigned short)); // 4MB
    float* xs    = (float*)alloc((size_t)B * M * sizeof(float));
    int*   iord  = (int*)alloc((size_t)B * M * sizeof(int));
    float* qcs   = (float*)alloc((size_t)B * N * sizeof(float));
    int*   qis   = (int*)alloc((size_t)B * N * sizeof(int));
    int*   bst   = (int*)alloc((size_t)B * (NB + 1) * sizeof(int));

    bin_kernel<<<8, 1024, 0, stream>>>(xz, x, bst, xs, iord, qcs, qis);
    permz_kernel<<<512, 256, 0, stream>>>(z, iord, zs);
    gather_kernel<<<B * (N / QG), 256, 0, stream>>>(ls, bst, xs, qcs, qis, zs, out);
}

// Round 2
// 87.165 us; speedup vs baseline: 1.0930x; 1.0930x over previous
//
#include <hip/hip_runtime.h>
#include <math.h>

#define B 4
#define N 4096
#define M 8192
#define C 64
#define NB 2048
#define XMIN (-64.0f)
#define INV_BW 16.0f   // bucket width 0.0625
#define CUT 10.0f      // truncation at exp(-10): err ~0.008 << tolerance
#define QG2 32         // queries per gather block (2 MFMA M-tiles)

typedef __attribute__((ext_vector_type(8))) short short8;   // 8 bf16 / 16B
typedef __attribute__((ext_vector_type(4))) float f32x4;

__device__ __forceinline__ int bucket_of(float v) {
    int k = (int)floorf((v - XMIN) * INV_BW);
    return min(max(k, 0), NB - 1);
}

__device__ __forceinline__ unsigned short f2bf(float f) {   // RNE fp32->bf16
    unsigned int u = __float_as_uint(f);
    return (unsigned short)((u + 0x7FFF + ((u >> 16) & 1)) >> 16);
}

// Blocks 0..3: bin points (batch b) -> bucket_start, xs, islot (m -> slot).
// Blocks 4..7: bin queries (batch b) -> qcs/qis. Wave-shuffle scan.
__global__ __launch_bounds__(1024) void bin_kernel(
    const float* __restrict__ xz, const float* __restrict__ x,
    int* __restrict__ bucket_start,    // [B][NB+1]
    float* __restrict__ xs,            // [B*M] sorted point coords
    int* __restrict__ islot,           // [B][M] original m -> sorted slot
    float* __restrict__ qcs,           // [B][N] sorted query coords
    int* __restrict__ qis)             // [B][N] sorted slot -> original n
{
    const int t    = threadIdx.x;
    const int lane = t & 63;
    const int w    = t >> 6;

    __shared__ int hist[NB];
    __shared__ int run[NB];
    __shared__ int wsum[16];
    const bool isQ = blockIdx.x >= 4;
    const int  b   = blockIdx.x & 3;
    const int  PT  = isQ ? (N / 1024) : (M / 1024);
    const float* src = isQ ? (x + b * N) : (xz + b * M);

    hist[t] = 0; hist[t + 1024] = 0;
    __syncthreads();

    float pv[8]; int pk[8];
    for (int j = 0; j < PT; ++j) {
        float v = src[j * 1024 + t];
        pv[j] = v; pk[j] = bucket_of(v);
        atomicAdd(&hist[pk[j]], 1);
    }
    __syncthreads();

    const int h0 = hist[2 * t], h1 = hist[2 * t + 1];
    const int tot = h0 + h1;
    int s = tot;
    #pragma unroll
    for (int off = 1; off < 64; off <<= 1) {
        int up = __shfl_up(s, off, 64);
        if (lane >= off) s += up;
    }
    if (lane == 63) wsum[w] = s;
    __syncthreads();
    int woff = 0;
    for (int i = 0; i < w; ++i) woff += wsum[i];
    const int excl = woff + s - tot;

    run[2 * t]     = excl;
    run[2 * t + 1] = excl + h0;
    if (!isQ) {
        bucket_start[b * (NB + 1) + 2 * t]     = excl;
        bucket_start[b * (NB + 1) + 2 * t + 1] = excl + h0;
        if (t == 1023) bucket_start[b * (NB + 1) + NB] = woff + s;  // == M
    }
    __syncthreads();

    if (!isQ) {
        for (int j = 0; j < PT; ++j) {
            int slot = atomicAdd(&run[pk[j]], 1);
            xs[b * M + slot]            = pv[j];
            islot[b * M + j * 1024 + t] = slot;
        }
    } else {
        for (int j = 0; j < PT; ++j) {
            int slot = atomicAdd(&run[pk[j]], 1);
            qcs[b * N + slot] = pv[j];
            qis[b * N + slot] = j * 1024 + t;
        }
    }
}

// 512 blocks: permute z [B,C,M] into bf16 sorted-row layout zrow[slot][C].
// Coalesced reads (contiguous m), LDS transpose, 128B-granular row writes.
__global__ __launch_bounds__(1024) void permz_kernel(
    const float* __restrict__ z, const int* __restrict__ islot,
    unsigned short* __restrict__ zrow)  // [B*M][C] bf16
{
    const int t  = threadIdx.x;
    const int b  = blockIdx.x >> 7;
    const int m0 = (blockIdx.x & 127) * 64;
    __shared__ float tile[64][65];
    __shared__ int slot_s[64];

    const int m = t & 63;
    #pragma unroll
    for (int k = 0; k < 4; ++k) {
        int c = (t >> 6) + 16 * k;
        tile[c][m] = z[((size_t)b * C + c) * M + m0 + m];   // coalesced in m
    }
    if (t < 64) slot_s[t] = islot[b * M + m0 + t];
    __syncthreads();

    const int j  = t >> 4;
    const int c4 = t & 15;
    ushort4 v4;
    v4.x = f2bf(tile[c4 * 4 + 0][j]);
    v4.y = f2bf(tile[c4 * 4 + 1][j]);
    v4.z = f2bf(tile[c4 * 4 + 2][j]);
    v4.w = f2bf(tile[c4 * 4 + 3][j]);
    ((ushort4*)zrow)[((size_t)b * M + slot_s[j]) * 16 + c4] = v4;
}

// 512 blocks (B x 128 chunks), 256 threads: zrow[slot][C] ->
// zs[b][ck][c 0..63][64 points], 16B blocks inside each 128B row XOR-swizzled
// by (c&7) so gather's ds_read_b128 is bank-conflict-free. Reads are scalar
// u16 but L1-served (32 threads share each 64B line); writes coalesced 16B.
__global__ __launch_bounds__(256) void transp_kernel(
    const unsigned short* __restrict__ zrow,
    unsigned short* __restrict__ zs)   // [B][128][4096] ushort (8KB chunks)
{
    const int t   = threadIdx.x;
    const int b   = blockIdx.x >> 7;
    const int ck  = blockIdx.x & 127;
    const int c   = t >> 2;            // channel 0..63
    const int seg = t & 3;             // 16-point segment

    const unsigned short* src = zrow + ((size_t)(b * M + ck * 64)) * 64 + c;
    unsigned short* dst = zs + ((size_t)b * 128 + ck) * 4096 + c * 64;

    #pragma unroll
    for (int h = 0; h < 2; ++h) {
        const int pb = seg * 2 + h;    // 8-point block 0..7
        short8 v;
        #pragma unroll
        for (int j = 0; j < 8; ++j)
            v[j] = (short)src[(size_t)(pb * 8 + j) * 64];
        *(short8*)(dst + (((pb ^ (c & 7)) << 3))) = v;
    }
}

// One block per 32 sorted queries; 8 waves; mfma_f32_16x16x32_bf16.
// wave w -> (query tile qt = w>>2, channel tile ct = w&3).
// Double-buffered LDS: stage chunk i+1 + compute its weights while MFMA'ing
// chunk i -> ONE barrier per chunk. B-frag = single ds_read_b128 from the
// swizzled chunk-transposed tile. 64-aligned windows -> no masking.
__global__ __launch_bounds__(512) void gather_kernel(
    const float* __restrict__ log_scale,
    const int* __restrict__ bucket_start,
    const float* __restrict__ xs,
    const float* __restrict__ qcs,
    const int* __restrict__ qis,
    const unsigned short* __restrict__ zs,   // chunk-transposed swizzled bf16
    float* __restrict__ out)                 // [B][N][C]
{
    const int t    = threadIdx.x;
    const int lane = t & 63;
    const int w    = t >> 6;            // wave 0..7
    const int quad = lane >> 4;         // 0..3
    const int low4 = lane & 15;
    const int qt   = w >> 2;            // query tile 0..1
    const int ct   = w & 3;             // channel tile 0..3
    // XCD-aware bijective swizzle (512 blocks, 512%8==0)
    const int gid = blockIdx.x;
    const int swz = (gid & 7) * 64 + (gid >> 3);
    const int b   = swz >> 7;           // 128 groups per batch
    const int g0  = (swz & 127) * QG2;

    __shared__ unsigned short zr[2][64 * 64];  // 2 x 8KB chunk tiles
    __shared__ unsigned short wl[2][QG2][72];  // 2 x padded weight tiles
    __shared__ float qcS[QG2];
    __shared__ int   qiS[QG2];

    const float ls   = log_scale[0];
    const float coef = -0.5f * __expf(-2.0f * ls);   // negative
    const float R    = sqrtf(CUT / (-coef));

    if (t < QG2) {
        qcS[t] = qcs[b * N + g0 + t];
        qiS[t] = qis[b * N + g0 + t];
    }
    __syncthreads();

    float xmin = qcS[0], xmax = qcS[0];
    #pragma unroll
    for (int j = 1; j < QG2; ++j) {
        xmin = fminf(xmin, qcS[j]);
        xmax = fmaxf(xmax, qcS[j]);
    }
    const int s0 = bucket_start[b * (NB + 1) + bucket_of(xmin - R)];
    const int s1 = bucket_start[b * (NB + 1) + bucket_of(xmax + R) + 1];
    const int e0 = s0 & ~63;                 // 64-aligned window; M%64==0
    const int e1 = (s1 + 63) & ~63;          // so [e0,e1) stays in [0,M]
    const int nck = (e1 - e0) >> 6;

    // weight-phase mapping: lane computes query qw, points pg*4..+3
    const int qw  = w * 4 + quad;            // 0..31
    const int pg  = low4;                    // point group (x4)
    const float qv = qcS[qw];
    const int row = ct * 16 + low4;          // this lane's B-frag channel row

    const float* xsb = xs + b * M;
    const unsigned short* zcb = zs + (size_t)b * M * C;  // 128 chunks x 4096

    f32x4 acc = {0.f, 0.f, 0.f, 0.f};

    // stage chunk i into LDS buffer p (async) + compute its weights into wl[p]
    auto STAGE_W = [&](int i, int p) {
        const unsigned short* gsrc =
            zcb + ((size_t)((e0 >> 6) + i)) * 4096 + w * 512 + lane * 8;
        __builtin_amdgcn_global_load_lds(
            (const __attribute__((address_space(1))) void*)gsrc,
            (__attribute__((address_space(3))) void*)(&zr[p][w * 512]),
            16, 0, 0);
        const float4 xp4 = *(const float4*)(xsb + e0 + i * 64 + pg * 4);
        float d0 = qv - xp4.x, d1 = qv - xp4.y;
        float d2 = qv - xp4.z, d3 = qv - xp4.w;
        ushort4 wv;
        wv.x = f2bf(__expf(coef * d0 * d0));
        wv.y = f2bf(__expf(coef * d1 * d1));
        wv.z = f2bf(__expf(coef * d2 * d2));
        wv.w = f2bf(__expf(coef * d3 * d3));
        *(ushort4*)&wl[p][qw][pg * 4] = wv;
    };

    if (nck > 0) STAGE_W(0, 0);
    __syncthreads();                          // zr[0]/wl[0] ready

    for (int i = 0; i < nck; ++i) {
        const int cur = i & 1;
        if (i + 1 < nck) STAGE_W(i + 1, cur ^ 1);   // overlaps MFMA below
        #pragma unroll
        for (int kh = 0; kh < 2; ++kh) {
            short8 afrag = *(const short8*)&wl[cur][qt * 16 + low4][kh * 32 + quad * 8];
            short8 bfrag = *(const short8*)
                &zr[cur][row * 64 + (((kh * 4 + quad) ^ (row & 7)) << 3)];
            acc = __builtin_amdgcn_mfma_f32_16x16x32_bf16(afrag, bfrag, acc, 0, 0, 0);
        }
        __syncthreads();                      // drains next-chunk loads + wl
    }

    // D: row(query, within tile) = quad*4 + r, col(channel local) = low4
    #pragma unroll
    for (int r = 0; r < 4; ++r) {
        const int q = qt * 16 + quad * 4 + r;
        out[((size_t)b * N + qiS[q]) * C + ct * 16 + low4] = acc[r];
    }
}

extern "C" void kernel_launch(void* const* d_in, const int* in_sizes, int n_in,
                              void* d_out, int out_size, void* d_ws, size_t ws_size,
                              hipStream_t stream) {
    const float* xz = (const float*)d_in[0];  // [B,M,1]
    const float* z  = (const float*)d_in[1];  // [B,C,M]
    const float* x  = (const float*)d_in[2];  // [B,N,1]
    const float* ls = (const float*)d_in[3];  // scalar
    float* out = (float*)d_out;               // [B,N,C]

    char* ws = (char*)d_ws;
    size_t off = 0;
    auto alloc = [&](size_t bytes) { void* p = ws + off; off += (bytes + 255) & ~size_t(255); return p; };

    unsigned short* zrow = (unsigned short*)alloc(((size_t)B * M + 64) * C * sizeof(unsigned short)); // ~4.2MB
    unsigned short* zs   = (unsigned short*)alloc((size_t)B * M * C * sizeof(unsigned short));        // 4MB
    float* xs    = (float*)alloc(((size_t)B * M + 64) * sizeof(float));
    int*   islot = (int*)alloc((size_t)B * M * sizeof(int));
    float* qcs   = (float*)alloc((size_t)B * N * sizeof(float));
    int*   qis   = (int*)alloc((size_t)B * N * sizeof(int));
    int*   bst   = (int*)alloc((size_t)B * (NB + 1) * sizeof(int));

    bin_kernel<<<8, 1024, 0, stream>>>(xz, x, bst, xs, islot, qcs, qis);
    permz_kernel<<<512, 1024, 0, stream>>>(z, islot, zrow);
    transp_kernel<<<512, 256, 0, stream>>>(zrow, zs);
    gather_kernel<<<B * (N / QG2), 512, 0, stream>>>(ls, bst, xs, qcs, qis, zs, out);
}

// Round 3
// 83.886 us; speedup vs baseline: 1.1357x; 1.0391x over previous
//
#include <hip/hip_runtime.h>
#include <math.h>

#define B 4
#define N 4096
#define M 8192
#define C 64
#define NB 2048
#define XMIN (-64.0f)
#define INV_BW 16.0f   // bucket width 0.0625
#define CUT 10.0f      // truncation at exp(-10): err ~0.008 << tolerance
#define QG 16          // queries per group == MFMA M
#define NSUBP 4        // point sub-blocks per batch (2048 elems each)
#define NSUBQ 2        // query sub-blocks per batch (2048 elems each)

typedef __attribute__((ext_vector_type(8))) short short8;   // 8 bf16
typedef __attribute__((ext_vector_type(4))) float f32x4;

__device__ __forceinline__ int bucket_of(float v) {
    int k = (int)floorf((v - XMIN) * INV_BW);
    return min(max(k, 0), NB - 1);
}

__device__ __forceinline__ unsigned short f2bf(float f) {   // RNE fp32->bf16
    unsigned int u = __float_as_uint(f);
    return (unsigned short)((u + 0x7FFF + ((u >> 16) & 1)) >> 16);
}

// 24 blocks x 256: privatized LDS histograms over 2048-element sub-ranges.
// blocks 0..15: points (b = bid>>2, sub = bid&3); 16..23: queries.
// part[bid][NB] fully written (incl. zeros) -> no zeroing race, no global atomics.
__global__ __launch_bounds__(256) void hist_kernel(
    const float* __restrict__ xz, const float* __restrict__ x,
    int* __restrict__ part)            // [24][NB]
{
    const int t   = threadIdx.x;
    const int bid = blockIdx.x;
    __shared__ int h[NB];
    #pragma unroll
    for (int i = 0; i < 8; ++i) h[t + 256 * i] = 0;
    __syncthreads();

    const bool isQ = bid >= 16;
    const int  b   = isQ ? (bid - 16) >> 1 : bid >> 2;
    const int  sub = isQ ? (bid - 16) & 1  : bid & 3;
    const float* src = (isQ ? x + b * N : xz + b * M) + sub * 2048;

    #pragma unroll
    for (int j = 0; j < 2; ++j) {
        float4 v4 = *(const float4*)(src + t * 4 + j * 1024);
        atomicAdd(&h[bucket_of(v4.x)], 1);
        atomicAdd(&h[bucket_of(v4.y)], 1);
        atomicAdd(&h[bucket_of(v4.z)], 1);
        atomicAdd(&h[bucket_of(v4.w)], 1);
    }
    __syncthreads();
    #pragma unroll
    for (int i = 0; i < 8; ++i) part[bid * NB + t + 256 * i] = h[t + 256 * i];
}

// 24 blocks x 256: each block re-derives the full per-(b,kind) bucket scan
// from the partials (cheaper than a third launch), adds its prior-sub offsets,
// then ranks its own 2048 elements with block-local LDS atomics. Slot ranges
// across blocks are disjoint by construction -> no inter-block atomics.
__global__ __launch_bounds__(256) void scat_kernel(
    const float* __restrict__ xz, const float* __restrict__ x,
    const int* __restrict__ part,      // [24][NB]
    int* __restrict__ bucket_start,    // [B][NB+1]
    float* __restrict__ xs,            // [B*M] sorted point coords
    int* __restrict__ islot,           // [B][M] original m -> sorted slot
    float* __restrict__ qcs,           // [B][N] sorted query coords
    int* __restrict__ qis)             // [B][N] sorted slot -> original n
{
    const int t    = threadIdx.x;
    const int lane = t & 63;
    const int w    = t >> 6;
    const int bid  = blockIdx.x;
    const bool isQ = bid >= 16;
    const int  b   = isQ ? (bid - 16) >> 1 : bid >> 2;
    const int  sub = isQ ? (bid - 16) & 1  : bid & 3;
    const int  nsub = isQ ? NSUBQ : NSUBP;
    const int  pb0  = isQ ? 16 + b * 2 : b * 4;
    const float* src = (isQ ? x + b * N : xz + b * M) + sub * 2048;

    __shared__ int base[NB];
    __shared__ int cnt[NB];
    __shared__ int wsum[4];

    // per-thread 8 contiguous buckets: totals + prior-sub ("mine") counts
    int tot[8], mine[8];
    #pragma unroll
    for (int j = 0; j < 8; ++j) { tot[j] = 0; mine[j] = 0; }
    for (int s_ = 0; s_ < nsub; ++s_) {
        #pragma unroll
        for (int j = 0; j < 8; ++j) {
            const int v = part[(pb0 + s_) * NB + t * 8 + j];
            tot[j] += v;
            if (s_ < sub) mine[j] += v;
        }
    }
    int pre[8]; int tsum = 0;
    #pragma unroll
    for (int j = 0; j < 8; ++j) { pre[j] = tsum; tsum += tot[j]; }
    int s = tsum;
    #pragma unroll
    for (int off = 1; off < 64; off <<= 1) {
        int up = __shfl_up(s, off, 64);
        if (lane >= off) s += up;
    }
    if (lane == 63) wsum[w] = s;
    #pragma unroll
    for (int i = 0; i < 8; ++i) cnt[t + 256 * i] = 0;
    __syncthreads();
    int woff = 0;
    for (int i = 0; i < w; ++i) woff += wsum[i];
    const int excl = woff + s - tsum;            // exclusive start of bucket t*8
    #pragma unroll
    for (int j = 0; j < 8; ++j) base[t * 8 + j] = excl + pre[j] + mine[j];
    if (!isQ && sub == 0) {
        #pragma unroll
        for (int j = 0; j < 8; ++j)
            bucket_start[b * (NB + 1) + t * 8 + j] = excl + pre[j];
        if (t == 255) bucket_start[b * (NB + 1) + NB] = woff + s;   // == M
    }
    __syncthreads();

    #pragma unroll
    for (int j = 0; j < 2; ++j) {
        float4 v4 = *(const float4*)(src + t * 4 + j * 1024);
        float vv[4] = {v4.x, v4.y, v4.z, v4.w};
        #pragma unroll
        for (int c = 0; c < 4; ++c) {
            const int k    = bucket_of(vv[c]);
            const int slot = base[k] + atomicAdd(&cnt[k], 1);
            const int orig = sub * 2048 + t * 4 + j * 1024 + c;
            if (!isQ) {
                xs[b * M + slot]    = vv[c];
                islot[b * M + orig] = slot;
            } else {
                qcs[b * N + slot] = vv[c];
                qis[b * N + slot] = orig;
            }
        }
    }
}

// 512 blocks: permute z [B,C,M] into bf16 sorted-row layout zs[slot][C].
__global__ __launch_bounds__(1024) void permz_kernel(
    const float* __restrict__ z, const int* __restrict__ islot,
    unsigned short* __restrict__ zs)   // [B*M + slack][C] bf16
{
    const int t  = threadIdx.x;
    const int b  = blockIdx.x >> 7;
    const int m0 = (blockIdx.x & 127) * 64;
    __shared__ float tile[64][65];
    __shared__ int slot_s[64];

    const int m = t & 63;
    #pragma unroll
    for (int k = 0; k < 4; ++k) {
        int c = (t >> 6) + 16 * k;
        tile[c][m] = z[((size_t)b * C + c) * M + m0 + m];   // coalesced in m
    }
    if (t < 64) slot_s[t] = islot[b * M + m0 + t];
    __syncthreads();

    const int j  = t >> 4;
    const int c4 = t & 15;
    ushort4 v4;
    v4.x = f2bf(tile[c4 * 4 + 0][j]);
    v4.y = f2bf(tile[c4 * 4 + 1][j]);
    v4.z = f2bf(tile[c4 * 4 + 2][j]);
    v4.w = f2bf(tile[c4 * 4 + 3][j]);
    ((ushort4*)zs)[((size_t)b * M + slot_s[j]) * 16 + c4] = v4;
}

// One block per 16 sorted queries; 4 waves; mfma_f32_16x16x32_bf16.
// Weights computed ONCE per block (4 exp/lane) into padded LDS wl;
// A-fragments = ds_read_b128 from wl; 64-aligned windows -> no masking
// (extra slots are real points with true weights; reference sums all M).
__global__ __launch_bounds__(256) void gather_kernel(
    const float* __restrict__ log_scale,
    const int* __restrict__ bucket_start,
    const float* __restrict__ xs,
    const float* __restrict__ qcs,
    const int* __restrict__ qis,
    const unsigned short* __restrict__ zs,   // [B*M + slack][C] bf16
    float* __restrict__ out)                 // [B][N][C]
{
    const int t    = threadIdx.x;
    const int lane = t & 63;
    const int w    = t >> 6;            // wave 0..3 -> channels w*16..+15
    const int quad = lane >> 4;         // 0..3
    const int low4 = lane & 15;
    const int g  = blockIdx.x;
    const int b  = g >> 8;              // 256 groups per batch
    const int g0 = (g & 255) * QG;

    __shared__ unsigned short zr[64 * 64];   // 8 KB: 64 rows x 64 ch bf16
    __shared__ unsigned short wl[QG][72];    // 2.25 KB padded (144B rows)
    __shared__ float qcS[QG];
    __shared__ int   qiS[QG];

    const float ls   = log_scale[0];
    const float coef = -0.5f * __expf(-2.0f * ls);   // negative
    const float R    = sqrtf(CUT / (-coef));

    if (t < QG) {
        qcS[t] = qcs[b * N + g0 + t];
        qiS[t] = qis[b * N + g0 + t];
    }
    __syncthreads();

    float xmin = qcS[0], xmax = qcS[0];
    #pragma unroll
    for (int j = 1; j < QG; ++j) {
        xmin = fminf(xmin, qcS[j]);
        xmax = fmaxf(xmax, qcS[j]);
    }
    const int s0 = bucket_start[b * (NB + 1) + bucket_of(xmin - R)];
    const int s1 = bucket_start[b * (NB + 1) + bucket_of(xmax + R) + 1];
    const int e0 = s0 & ~63;                 // 64-aligned window; M%64==0
    const int e1 = (s1 + 63) & ~63;          // so [e0,e1) stays in [0,M]

    // weight-phase mapping: this lane computes queries qw, points pg*4..+3
    const int qw = w * 4 + (lane >> 4);      // 0..15
    const int pg = lane & 15;                // point group (x4)
    const float qv = qcS[qw];

    f32x4 acc = {0.f, 0.f, 0.f, 0.f};

    const float* xsb = xs + b * M;
    const unsigned short* zsb = zs + (size_t)b * M * C;

    for (int cs = e0; cs < e1; cs += 64) {
        __syncthreads();                 // zr/wl free from previous chunk
        // stage rows cs..cs+63 (128B bf16 rows): 2 global_load_lds per wave
        #pragma unroll
        for (int r = 0; r < 2; ++r) {
            const unsigned short* gp =
                zsb + ((size_t)cs + (w * 2 + r) * 8 + (lane >> 3)) * C + (lane & 7) * 8;
            unsigned short* lp = zr + (w * 2 + r) * 512;   // wave-uniform base
            __builtin_amdgcn_global_load_lds(
                (const __attribute__((address_space(1))) void*)gp,
                (__attribute__((address_space(3))) void*)lp, 16, 0, 0);
        }
        // block-shared weights (overlap the staging): 4 exp per lane
        {
            const float4 xp4 = *(const float4*)(xsb + cs + pg * 4);  // 16B-aligned
            float d0 = qv - xp4.x, d1 = qv - xp4.y;
            float d2 = qv - xp4.z, d3 = qv - xp4.w;
            ushort4 wv;
            wv.x = f2bf(__expf(coef * d0 * d0));
            wv.y = f2bf(__expf(coef * d1 * d1));
            wv.z = f2bf(__expf(coef * d2 * d2));
            wv.w = f2bf(__expf(coef * d3 * d3));
            *(ushort4*)&wl[qw][pg * 4] = wv;
        }
        __syncthreads();                 // zr staged + wl written
        // A = weights via b128 (padded rows), B = zr scalar u16, 2 MFMA
        #pragma unroll
        for (int kh = 0; kh < 2; ++kh) {
            short8 afrag = *(const short8*)&wl[low4][kh * 32 + quad * 8];
            short8 bfrag;
            #pragma unroll
            for (int j = 0; j < 8; ++j) {
                const int p = kh * 32 + quad * 8 + j;
                bfrag[j] = (short)zr[p * 64 + w * 16 + low4];
            }
            acc = __builtin_amdgcn_mfma_f32_16x16x32_bf16(afrag, bfrag, acc, 0, 0, 0);
        }
    }

    // D: row(query) = quad*4 + r, col(channel local) = low4
    #pragma unroll
    for (int r = 0; r < 4; ++r) {
        const int q = quad * 4 + r;
        out[((size_t)b * N + qiS[q]) * C + w * 16 + low4] = acc[r];
    }
}

extern "C" void kernel_launch(void* const* d_in, const int* in_sizes, int n_in,
                              void* d_out, int out_size, void* d_ws, size_t ws_size,
                              hipStream_t stream) {
    const float* xz = (const float*)d_in[0];  // [B,M,1]
    const float* z  = (const float*)d_in[1];  // [B,C,M]
    const float* x  = (const float*)d_in[2];  // [B,N,1]
    const float* ls = (const float*)d_in[3];  // scalar
    float* out = (float*)d_out;               // [B,N,C]

    char* ws = (char*)d_ws;
    size_t off = 0;
    auto alloc = [&](size_t bytes) { void* p = ws + off; off += (bytes + 255) & ~size_t(255); return p; };

    unsigned short* zs = (unsigned short*)alloc(((size_t)B * M + 64) * C * sizeof(unsigned short)); // ~4.2MB
    float* xs    = (float*)alloc(((size_t)B * M + 64) * sizeof(float));
    int*   islot = (int*)alloc((size_t)B * M * sizeof(int));
    float* qcs   = (float*)alloc((size_t)B * N * sizeof(float));
    int*   qis   = (int*)alloc((size_t)B * N * sizeof(int));
    int*   bst   = (int*)alloc((size_t)B * (NB + 1) * sizeof(int));
    int*   part  = (int*)alloc((size_t)24 * NB * sizeof(int));

    hist_kernel<<<24, 256, 0, stream>>>(xz, x, part);
    scat_kernel<<<24, 256, 0, stream>>>(xz, x, part, bst, xs, islot, qcs, qis);
    permz_kernel<<<512, 1024, 0, stream>>>(z, islot, zs);
    gather_kernel<<<B * (N / QG), 256, 0, stream>>>(ls, bst, xs, qcs, qis, zs, out);
}